// Round 1
// baseline (536.625 us; speedup 1.0000x reference)
//
#include <hip/hip_runtime.h>
#include <hip/hip_bf16.h>

typedef __bf16 bf16_t;
typedef __bf16 bf16x4 __attribute__((ext_vector_type(4)));
typedef __bf16 bf16x8 __attribute__((ext_vector_type(8)));
typedef float f32x4 __attribute__((ext_vector_type(4)));

// Problem dims (fixed): B=8, S=512, D=1024, H=16, DK=64; M=B*S=4096, N=K=1024.

__device__ __forceinline__ f32x4 mfma16(bf16x8 a, bf16x8 b, f32x4 c) {
    return __builtin_amdgcn_mfma_f32_16x16x32_bf16(a, b, c, 0, 0, 0);
}

__device__ __forceinline__ float blendf(float s, int am, int hm, float hv) {
    s = am ? -1e9f : s;
    return hm ? 0.5f * hv + 0.5f * s : s;
}

// ---------- prep: fp32 -> bf16 cast (x) ----------
__global__ __launch_bounds__(256) void cast_kernel(const float* __restrict__ x,
                                                   bf16_t* __restrict__ xb) {
    size_t i = ((size_t)blockIdx.x * 256 + threadIdx.x) * 4;
    float4 v = *(const float4*)(x + i);
    bf16x4 o;
    o[0] = (bf16_t)v.x; o[1] = (bf16_t)v.y; o[2] = (bf16_t)v.z; o[3] = (bf16_t)v.w;
    *(bf16x4*)(xb + i) = o;
}

// ---------- prep: W [K=1024][N=1024] f32 -> Wt [N][K] bf16 ----------
__global__ __launch_bounds__(256) void transpose_kernel(const float* __restrict__ W,
                                                        bf16_t* __restrict__ Wt) {
    __shared__ float tile[32][33];
    int tx = threadIdx.x & 31, ty = threadIdx.x >> 5;  // 32x8
    int bx = blockIdx.x * 32, by = blockIdx.y * 32;    // bx: n, by: k
#pragma unroll
    for (int j = 0; j < 4; j++)
        tile[ty + j * 8][tx] = W[(size_t)(by + ty + j * 8) * 1024 + bx + tx];
    __syncthreads();
#pragma unroll
    for (int j = 0; j < 4; j++)
        Wt[(size_t)(bx + ty + j * 8) * 1024 + by + tx] = (bf16_t)tile[tx][ty + j * 8];
}

// ---------- GEMM: C[m][n] = A[m][:] . Bt[n][:] + bias[n], various epilogues ----------
// MODE 0: write bf16 [B,H,S,DK]   (Q and K layouts)
// MODE 2: write bf16 [B,H,DK,S]   (V transposed for PV mfma A-fragments)
// MODE 3: write f32  [M,N] = v + resid[m][n]   (output proj + residual, pre-LN)
template <int MODE>
__global__ __launch_bounds__(256) void gemm_bt(const bf16_t* __restrict__ A,
                                               const bf16_t* __restrict__ Bt,
                                               const float* __restrict__ bias,
                                               const float* __restrict__ resid,
                                               void* __restrict__ outp) {
    constexpr int K = 1024, N = 1024;
    __shared__ bf16_t As[128][40];  // +8 pad: stride 80B = 20 banks -> 2-way (free)
    __shared__ bf16_t Bs[128][40];
    const int t = threadIdx.x;
    const int lane = t & 63;
    const int wv = t >> 6;
    const int lm = lane & 15, q4 = lane >> 4;
    const int mblk = blockIdx.y * 128, nblk = blockIdx.x * 128;
    const int mrow = (wv & 1) * 64, ncol = (wv >> 1) * 64;

    f32x4 acc[4][4];
#pragma unroll
    for (int r = 0; r < 4; r++)
#pragma unroll
        for (int c = 0; c < 4; c++) acc[r][c] = (f32x4){0.f, 0.f, 0.f, 0.f};

    for (int k0 = 0; k0 < K; k0 += 32) {
#pragma unroll
        for (int ld = 0; ld < 2; ld++) {
            int id = t + ld * 256;
            int r = id >> 2, c = (id & 3) * 8;
            *(bf16x8*)&As[r][c] = *(const bf16x8*)&A[(size_t)(mblk + r) * K + k0 + c];
            *(bf16x8*)&Bs[r][c] = *(const bf16x8*)&Bt[(size_t)(nblk + r) * K + k0 + c];
        }
        __syncthreads();
        bf16x8 af[4], bf[4];
#pragma unroll
        for (int r = 0; r < 4; r++) af[r] = *(const bf16x8*)&As[mrow + r * 16 + lm][q4 * 8];
#pragma unroll
        for (int c = 0; c < 4; c++) bf[c] = *(const bf16x8*)&Bs[ncol + c * 16 + lm][q4 * 8];
#pragma unroll
        for (int r = 0; r < 4; r++)
#pragma unroll
            for (int c = 0; c < 4; c++) acc[r][c] = mfma16(af[r], bf[c], acc[r][c]);
        __syncthreads();
    }

#pragma unroll
    for (int r = 0; r < 4; r++)
#pragma unroll
        for (int c = 0; c < 4; c++)
#pragma unroll
            for (int i = 0; i < 4; i++) {
                int m = mblk + mrow + r * 16 + q4 * 4 + i;
                int n = nblk + ncol + c * 16 + lm;
                float v = acc[r][c][i] + bias[n];
                if (MODE == 0) {
                    int b = m >> 9, s = m & 511, h = n >> 6, d = n & 63;
                    ((bf16_t*)outp)[(((size_t)(b * 16 + h) * 512) + s) * 64 + d] = (bf16_t)v;
                } else if (MODE == 2) {
                    int b = m >> 9, s = m & 511, h = n >> 6, d = n & 63;
                    ((bf16_t*)outp)[(((size_t)(b * 16 + h) * 64) + d) * 512 + s] = (bf16_t)v;
                } else {
                    ((float*)outp)[(size_t)m * N + n] = v + resid[(size_t)m * N + n];
                }
            }
}

// ---------- FUSED: scores^T = K·Q^T/8 -> LDS -> blend+softmax (coalesced) -> attn out
//                   + P (bf16, LDS) -> PV MFMA -> xo
// grid: (S/16=32, B*H=128); block 256 = 4 waves.
// Phase 1: wave wv computes scores for keys [wv*128, wv*128+128) x 16 q rows -> S lds.
// Phase 2: wave wv owns q rows [wv*4, wv*4+4); 64 lanes stream 512 keys/row with
//          float4/int4 fully-coalesced loads of help_vals/help_mask/attn_mask, row
//          softmax entirely in-wave, coalesced attn_out store, P (normalized bf16) -> lds.
// Phase 3: wave wv computes partial ctx^T over its 128 keys via mfma(Vt, P).
// Phase 4: cross-wave reduce through lds (overlaying S), coalesced xo store.
__global__ __launch_bounds__(256) void attn_fused_kernel(const bf16_t* __restrict__ Qb,
                                                         const bf16_t* __restrict__ Kb,
                                                         const bf16_t* __restrict__ Vt,
                                                         const float* __restrict__ help_vals,
                                                         const int* __restrict__ help_mask,
                                                         const int* __restrict__ attn_mask,
                                                         float* __restrict__ attn_out,
                                                         bf16_t* __restrict__ xo) {
    const int t = threadIdx.x;
    const int lane = t & 63, wv = t >> 6;
    const int lm = lane & 15, q4 = lane >> 4;
    const int bh = blockIdx.y;
    const int b = bh >> 4, h = bh & 15;
    const int q0 = blockIdx.x * 16;
    const bf16_t* Qp = Qb + (size_t)bh * 512 * 64;
    const bf16_t* Kp = Kb + (size_t)bh * 512 * 64;
    const bf16_t* Vp = Vt + (size_t)bh * 64 * 512;  // [dk][s]

    // stride 532 f32: 532%32=20 -> phase-1 16B writes land 2-way (free)
    __shared__ float S[16][532];     // 34 KB scores; reused as red[4][16][68] in phase 4
    // stride 552 bf16: (552/2)%32=20 -> phase-3 b128 reads land 2-way (free)
    __shared__ bf16_t Pl[16][552];   // 17.3 KB normalized P

    // ---- phase 1: QK^T (transposed mfma: A=K rows, B=Q rows) ----
    const bf16x8 bq0 = *(const bf16x8*)&Qp[(size_t)(q0 + lm) * 64 + q4 * 8];
    const bf16x8 bq1 = *(const bf16x8*)&Qp[(size_t)(q0 + lm) * 64 + 32 + q4 * 8];

    f32x4 acc[8];
#pragma unroll
    for (int kt = 0; kt < 8; kt++) acc[kt] = (f32x4){0.f, 0.f, 0.f, 0.f};
#pragma unroll
    for (int kt = 0; kt < 8; kt++) {
        const int krow = wv * 128 + kt * 16 + lm;
        bf16x8 ak0 = *(const bf16x8*)&Kp[(size_t)krow * 64 + q4 * 8];
        bf16x8 ak1 = *(const bf16x8*)&Kp[(size_t)krow * 64 + 32 + q4 * 8];
        acc[kt] = mfma16(ak0, bq0, acc[kt]);
        acc[kt] = mfma16(ak1, bq1, acc[kt]);
    }
    // lane holds D[key = wv*128+kt*16+q4*4+i][q = lm]; scale and dump to S
#pragma unroll
    for (int kt = 0; kt < 8; kt++) {
        f32x4 sv = acc[kt] * 0.125f;
        *(f32x4*)&S[lm][wv * 128 + kt * 16 + q4 * 4] = sv;
    }
    __syncthreads();

    // ---- phase 2: blend + softmax, 4 q rows per wave, coalesced streams ----
#pragma unroll 2
    for (int rr = 0; rr < 4; rr++) {
        const int r = wv * 4 + rr;
        const int q = q0 + r;
        const size_t qrow = ((size_t)bh * 512 + q) * 512;
        const size_t arow = ((size_t)b * 512 + q) * 512;
        const int c0 = lane * 4;
        const int c1 = 256 + lane * 4;
        f32x4 s0 = *(const f32x4*)&S[r][c0];
        f32x4 s1 = *(const f32x4*)&S[r][c1];
        const float4 hv0 = *(const float4*)&help_vals[qrow + c0];
        const float4 hv1 = *(const float4*)&help_vals[qrow + c1];
        const int4 hm0 = *(const int4*)&help_mask[qrow + c0];
        const int4 hm1 = *(const int4*)&help_mask[qrow + c1];
        const int4 am0 = *(const int4*)&attn_mask[arow + c0];
        const int4 am1 = *(const int4*)&attn_mask[arow + c1];
        float s[8];
        s[0] = blendf(s0[0], am0.x, hm0.x, hv0.x);
        s[1] = blendf(s0[1], am0.y, hm0.y, hv0.y);
        s[2] = blendf(s0[2], am0.z, hm0.z, hv0.z);
        s[3] = blendf(s0[3], am0.w, hm0.w, hv0.w);
        s[4] = blendf(s1[0], am1.x, hm1.x, hv1.x);
        s[5] = blendf(s1[1], am1.y, hm1.y, hv1.y);
        s[6] = blendf(s1[2], am1.z, hm1.z, hv1.z);
        s[7] = blendf(s1[3], am1.w, hm1.w, hv1.w);
        float mloc = fmaxf(fmaxf(fmaxf(s[0], s[1]), fmaxf(s[2], s[3])),
                           fmaxf(fmaxf(s[4], s[5]), fmaxf(s[6], s[7])));
#pragma unroll
        for (int off = 1; off < 64; off <<= 1) mloc = fmaxf(mloc, __shfl_xor(mloc, off));
        float lsum = 0.f;
#pragma unroll
        for (int i = 0; i < 8; i++) {
            s[i] = __expf(s[i] - mloc);
            lsum += s[i];
        }
#pragma unroll
        for (int off = 1; off < 64; off <<= 1) lsum += __shfl_xor(lsum, off);
        const float rinv = 1.0f / lsum;
        float4 o0, o1;
        o0.x = s[0] * rinv; o0.y = s[1] * rinv; o0.z = s[2] * rinv; o0.w = s[3] * rinv;
        o1.x = s[4] * rinv; o1.y = s[5] * rinv; o1.z = s[6] * rinv; o1.w = s[7] * rinv;
        *(float4*)&attn_out[qrow + c0] = o0;
        *(float4*)&attn_out[qrow + c1] = o1;
        bf16x4 p0, p1;
        p0[0] = (bf16_t)o0.x; p0[1] = (bf16_t)o0.y; p0[2] = (bf16_t)o0.z; p0[3] = (bf16_t)o0.w;
        p1[0] = (bf16_t)o1.x; p1[1] = (bf16_t)o1.y; p1[2] = (bf16_t)o1.z; p1[3] = (bf16_t)o1.w;
        *(bf16x4*)&Pl[r][c0] = p0;
        *(bf16x4*)&Pl[r][c1] = p1;
    }
    __syncthreads();

    // ---- phase 3: PV. A = V^T rows (d), B = P^T (k=key, n=q) -> D = ctx^T[d][q] ----
    f32x4 acc2[4];
#pragma unroll
    for (int mt = 0; mt < 4; mt++) acc2[mt] = (f32x4){0.f, 0.f, 0.f, 0.f};
    const int kb0 = wv * 128;
#pragma unroll
    for (int C = 0; C < 4; C++) {
        const bf16x8 pf = *(const bf16x8*)&Pl[lm][kb0 + C * 32 + q4 * 8];
#pragma unroll
        for (int mt = 0; mt < 4; mt++) {
            const bf16x8 vf =
                *(const bf16x8*)&Vp[(size_t)(mt * 16 + lm) * 512 + kb0 + C * 32 + q4 * 8];
            acc2[mt] = mfma16(vf, pf, acc2[mt]);
        }
    }

    // ---- phase 4: cross-wave reduce (red overlays S; safe after phase-2 barrier) ----
    float* redp = &S[0][0];  // red[w][q][68]
#pragma unroll
    for (int mt = 0; mt < 4; mt++)
        *(f32x4*)(redp + ((wv * 16 + lm) * 68 + mt * 16 + q4 * 4)) = acc2[mt];
    __syncthreads();
    {
        const int qq = t >> 4;
        const int d4 = (t & 15) * 4;
        f32x4 r0 = *(const f32x4*)(redp + ((0 * 16 + qq) * 68 + d4));
        f32x4 r1 = *(const f32x4*)(redp + ((1 * 16 + qq) * 68 + d4));
        f32x4 r2 = *(const f32x4*)(redp + ((2 * 16 + qq) * 68 + d4));
        f32x4 r3 = *(const f32x4*)(redp + ((3 * 16 + qq) * 68 + d4));
        f32x4 sum = r0 + r1 + r2 + r3;
        bf16x4 o;
        o[0] = (bf16_t)sum[0]; o[1] = (bf16_t)sum[1];
        o[2] = (bf16_t)sum[2]; o[3] = (bf16_t)sum[3];
        *(bf16x4*)&xo[((size_t)(b * 512 + q0 + qq)) * 1024 + h * 64 + d4] = o;
    }
}

// ---------- LayerNorm over last dim (1024) ----------
__global__ __launch_bounds__(256) void layernorm_kernel(const float* __restrict__ ypre,
                                                        const float* __restrict__ g,
                                                        const float* __restrict__ bvec,
                                                        float* __restrict__ out) {
    int row = blockIdx.x;
    int t = threadIdx.x;
    float4 v = ((const float4*)(ypre + (size_t)row * 1024))[t];
    float s = v.x + v.y + v.z + v.w;
    float sq = v.x * v.x + v.y * v.y + v.z * v.z + v.w * v.w;
#pragma unroll
    for (int off = 32; off; off >>= 1) {
        s += __shfl_down(s, off);
        sq += __shfl_down(sq, off);
    }
    __shared__ float ss[4], ssq[4];
    if ((t & 63) == 0) { ss[t >> 6] = s; ssq[t >> 6] = sq; }
    __syncthreads();
    float tot = ss[0] + ss[1] + ss[2] + ss[3];
    float totq = ssq[0] + ssq[1] + ssq[2] + ssq[3];
    float mu = tot * (1.0f / 1024.0f);
    float var = totq * (1.0f / 1024.0f) - mu * mu;
    float rstd = rsqrtf(var + 1e-5f);
    float4 gg = ((const float4*)g)[t];
    float4 bb = ((const float4*)bvec)[t];
    float4 o;
    o.x = (v.x - mu) * rstd * gg.x + bb.x;
    o.y = (v.y - mu) * rstd * gg.y + bb.y;
    o.z = (v.z - mu) * rstd * gg.z + bb.z;
    o.w = (v.w - mu) * rstd * gg.w + bb.w;
    ((float4*)(out + (size_t)row * 1024))[t] = o;
}

extern "C" void kernel_launch(void* const* d_in, const int* in_sizes, int n_in,
                              void* d_out, int out_size, void* d_ws, size_t ws_size,
                              hipStream_t stream) {
    const float* x         = (const float*)d_in[0];
    const float* Wq        = (const float*)d_in[1];
    const float* bq        = (const float*)d_in[2];
    const float* Wk        = (const float*)d_in[3];
    const float* bk        = (const float*)d_in[4];
    const float* Wv        = (const float*)d_in[5];
    const float* bv        = (const float*)d_in[6];
    const float* Wo        = (const float*)d_in[7];
    const float* bo        = (const float*)d_in[8];
    const float* ln_g      = (const float*)d_in[9];
    const float* ln_b      = (const float*)d_in[10];
    const float* help_vals = (const float*)d_in[11];
    const int*   help_mask = (const int*)d_in[12];
    const int*   attn_mask = (const int*)d_in[13];

    char* ws = (char*)d_ws;
    bf16_t* xb   = (bf16_t*)(ws);                       // 8 MB  [4096,1024]
    bf16_t* wqt  = (bf16_t*)(ws + ((size_t)8 << 20));   // 2 MB  [1024,1024] (N-major)
    bf16_t* wkt  = (bf16_t*)(ws + ((size_t)10 << 20));
    bf16_t* wvt  = (bf16_t*)(ws + ((size_t)12 << 20));
    bf16_t* wot  = (bf16_t*)(ws + ((size_t)14 << 20));
    bf16_t* qb   = (bf16_t*)(ws + ((size_t)16 << 20));  // 8 MB  [B,H,S,DK]
    bf16_t* kb   = (bf16_t*)(ws + ((size_t)24 << 20));  // 8 MB  [B,H,S,DK]
    bf16_t* vt   = (bf16_t*)(ws + ((size_t)32 << 20));  // 8 MB  [B,H,DK,S]
    bf16_t* xo   = (bf16_t*)(ws + ((size_t)40 << 20));  // 8 MB  [B,S,H*DK]
    float*  ypre = (float*)(ws + ((size_t)48 << 20));   // 16 MB [4096,1024]

    float* y_out = (float*)d_out;                      // [B,S,D] f32
    float* attn_out = y_out + (size_t)4096 * 1024;     // [B,H,S,S] f32

    cast_kernel<<<4096, 256, 0, stream>>>(x, xb);
    dim3 tg(32, 32);
    transpose_kernel<<<tg, 256, 0, stream>>>(Wq, wqt);
    transpose_kernel<<<tg, 256, 0, stream>>>(Wk, wkt);
    transpose_kernel<<<tg, 256, 0, stream>>>(Wv, wvt);
    transpose_kernel<<<tg, 256, 0, stream>>>(Wo, wot);

    dim3 gg(8, 32);  // N/128, M/128
    gemm_bt<0><<<gg, 256, 0, stream>>>(xb, wqt, bq, nullptr, qb);
    gemm_bt<0><<<gg, 256, 0, stream>>>(xb, wkt, bk, nullptr, kb);
    gemm_bt<2><<<gg, 256, 0, stream>>>(xb, wvt, bv, nullptr, vt);

    dim3 ga(32, 128);  // q tiles of 16, B*H
    attn_fused_kernel<<<ga, 256, 0, stream>>>(qb, kb, vt, help_vals, help_mask, attn_mask,
                                              attn_out, xo);

    gemm_bt<3><<<gg, 256, 0, stream>>>(xo, wot, bo, x, ypre);
    layernorm_kernel<<<4096, 256, 0, stream>>>(ypre, ln_g, ln_b, y_out);
}

// Round 2
// 478.151 us; speedup vs baseline: 1.1223x; 1.1223x over previous
//
#include <hip/hip_runtime.h>
#include <hip/hip_bf16.h>

typedef __bf16 bf16_t;
typedef __bf16 bf16x4 __attribute__((ext_vector_type(4)));
typedef __bf16 bf16x8 __attribute__((ext_vector_type(8)));
typedef float f32x4 __attribute__((ext_vector_type(4)));
typedef int i32x4 __attribute__((ext_vector_type(4)));

// Problem dims (fixed): B=8, S=512, D=1024, H=16, DK=64; M=B*S=4096, N=K=1024.

__device__ __forceinline__ f32x4 mfma16(bf16x8 a, bf16x8 b, f32x4 c) {
    return __builtin_amdgcn_mfma_f32_16x16x32_bf16(a, b, c, 0, 0, 0);
}

__device__ __forceinline__ float blendf(float s, int am, int hm, float hv) {
    s = am ? -1e9f : s;
    return hm ? 0.5f * hv + 0.5f * s : s;
}

// async global->LDS, 16B per lane
#define GLOAD_LDS16(g, l)                                                   \
    __builtin_amdgcn_global_load_lds(                                       \
        (const __attribute__((address_space(1))) void*)(g),                 \
        (__attribute__((address_space(3))) void*)(l), 16, 0, 0)

// ---------- prep: fp32 -> bf16 cast (x) ----------
__global__ __launch_bounds__(256) void cast_kernel(const float* __restrict__ x,
                                                   bf16_t* __restrict__ xb) {
    size_t i = ((size_t)blockIdx.x * 256 + threadIdx.x) * 4;
    float4 v = *(const float4*)(x + i);
    bf16x4 o;
    o[0] = (bf16_t)v.x; o[1] = (bf16_t)v.y; o[2] = (bf16_t)v.z; o[3] = (bf16_t)v.w;
    *(bf16x4*)(xb + i) = o;
}

// ---------- prep: W [K=1024][N=1024] f32 -> Wt [N][K] bf16, 4 weights in one launch ----
__global__ __launch_bounds__(256) void transpose_kernel(const float* __restrict__ Wq,
                                                        const float* __restrict__ Wk,
                                                        const float* __restrict__ Wv,
                                                        const float* __restrict__ Wo,
                                                        bf16_t* __restrict__ Wt_base) {
    __shared__ float tile[32][33];
    const int z = blockIdx.z;
    const float* W = (z == 0) ? Wq : (z == 1) ? Wk : (z == 2) ? Wv : Wo;
    bf16_t* Wt = Wt_base + ((size_t)z << 20);
    int tx = threadIdx.x & 31, ty = threadIdx.x >> 5;  // 32x8
    int bx = blockIdx.x * 32, by = blockIdx.y * 32;    // bx: n, by: k
#pragma unroll
    for (int j = 0; j < 4; j++)
        tile[ty + j * 8][tx] = W[(size_t)(by + ty + j * 8) * 1024 + bx + tx];
    __syncthreads();
#pragma unroll
    for (int j = 0; j < 4; j++)
        Wt[(size_t)(bx + ty + j * 8) * 1024 + by + tx] = (bf16_t)tile[tx][ty + j * 8];
}

// ---------- fused Q/K/V projection GEMM (z selects weight/bias/output) ----------
// 2-phase pipeline: global_load_lds (width 16) double-buffered, 1 barrier per K-step.
// z=0 -> qb [B,H,S,DK]; z=1 -> kb [B,H,S,DK]; z=2 -> vt [B,H,DK,S].
__global__ __launch_bounds__(256, 4) void gemm_qkv(const bf16_t* __restrict__ A,
                                                   const bf16_t* __restrict__ WtB,
                                                   const float* __restrict__ bq,
                                                   const float* __restrict__ bk,
                                                   const float* __restrict__ bv,
                                                   bf16_t* __restrict__ qb,
                                                   bf16_t* __restrict__ kb,
                                                   bf16_t* __restrict__ vt) {
    constexpr int K = 1024;
    __shared__ bf16_t As[2][128][32];  // linear (gload_lds requires contiguous dest)
    __shared__ bf16_t Bs[2][128][32];
    const int z = blockIdx.z;
    const bf16_t* Bt = WtB + ((size_t)z << 20);
    const float* bias = (z == 0) ? bq : (z == 1) ? bk : bv;
    const int t = threadIdx.x;
    const int lane = t & 63, wv = t >> 6;
    const int lm = lane & 15, q4 = lane >> 4;
    const int mblk = blockIdx.y * 128, nblk = blockIdx.x * 128;
    const int mrow = (wv & 1) * 64, ncol = (wv >> 1) * 64;
    const int sr = t >> 2, sc = (t & 3) * 8;  // staging: thread t covers 16B chunk t

    f32x4 acc[4][4];
#pragma unroll
    for (int r = 0; r < 4; r++)
#pragma unroll
        for (int c = 0; c < 4; c++) acc[r][c] = (f32x4){0.f, 0.f, 0.f, 0.f};

    const bf16_t* ga = &A[(size_t)(mblk + sr) * K + sc];
    const bf16_t* gb = &Bt[(size_t)(nblk + sr) * K + sc];
    GLOAD_LDS16(ga, &As[0][sr][sc]);
    GLOAD_LDS16(ga + (size_t)64 * K, &As[0][sr + 64][sc]);
    GLOAD_LDS16(gb, &Bs[0][sr][sc]);
    GLOAD_LDS16(gb + (size_t)64 * K, &Bs[0][sr + 64][sc]);
    __syncthreads();

    int cur = 0;
    for (int k0 = 0; k0 < K; k0 += 32) {
        if (k0 + 32 < K) {
            const bf16_t* ga2 = ga + k0 + 32;
            const bf16_t* gb2 = gb + k0 + 32;
            GLOAD_LDS16(ga2, &As[cur ^ 1][sr][sc]);
            GLOAD_LDS16(ga2 + (size_t)64 * K, &As[cur ^ 1][sr + 64][sc]);
            GLOAD_LDS16(gb2, &Bs[cur ^ 1][sr][sc]);
            GLOAD_LDS16(gb2 + (size_t)64 * K, &Bs[cur ^ 1][sr + 64][sc]);
        }
        bf16x8 af[4], bfr[4];
#pragma unroll
        for (int r = 0; r < 4; r++) af[r] = *(const bf16x8*)&As[cur][mrow + r * 16 + lm][q4 * 8];
#pragma unroll
        for (int c = 0; c < 4; c++) bfr[c] = *(const bf16x8*)&Bs[cur][ncol + c * 16 + lm][q4 * 8];
#pragma unroll
        for (int r = 0; r < 4; r++)
#pragma unroll
            for (int c = 0; c < 4; c++) acc[r][c] = mfma16(af[r], bfr[c], acc[r][c]);
        __syncthreads();
        cur ^= 1;
    }

#pragma unroll
    for (int r = 0; r < 4; r++)
#pragma unroll
        for (int c = 0; c < 4; c++)
#pragma unroll
            for (int i = 0; i < 4; i++) {
                int m = mblk + mrow + r * 16 + q4 * 4 + i;
                int n = nblk + ncol + c * 16 + lm;
                float v = acc[r][c][i] + bias[n];
                int b = m >> 9, s = m & 511, h = n >> 6, d = n & 63;
                if (z < 2) {
                    bf16_t* o = z ? kb : qb;
                    o[(((size_t)(b * 16 + h) * 512) + s) * 64 + d] = (bf16_t)v;
                } else {
                    vt[(((size_t)(b * 16 + h) * 64) + d) * 512 + s] = (bf16_t)v;
                }
            }
}

// ---------- output projection GEMM + residual -> ypre f32 ----------
__global__ __launch_bounds__(256, 4) void gemm_out(const bf16_t* __restrict__ A,
                                                   const bf16_t* __restrict__ Bt,
                                                   const float* __restrict__ bias,
                                                   const float* __restrict__ resid,
                                                   float* __restrict__ outp) {
    constexpr int K = 1024, N = 1024;
    __shared__ bf16_t As[2][128][32];
    __shared__ bf16_t Bs[2][128][32];
    const int t = threadIdx.x;
    const int lane = t & 63, wv = t >> 6;
    const int lm = lane & 15, q4 = lane >> 4;
    const int mblk = blockIdx.y * 128, nblk = blockIdx.x * 128;
    const int mrow = (wv & 1) * 64, ncol = (wv >> 1) * 64;
    const int sr = t >> 2, sc = (t & 3) * 8;

    f32x4 acc[4][4];
#pragma unroll
    for (int r = 0; r < 4; r++)
#pragma unroll
        for (int c = 0; c < 4; c++) acc[r][c] = (f32x4){0.f, 0.f, 0.f, 0.f};

    const bf16_t* ga = &A[(size_t)(mblk + sr) * K + sc];
    const bf16_t* gb = &Bt[(size_t)(nblk + sr) * K + sc];
    GLOAD_LDS16(ga, &As[0][sr][sc]);
    GLOAD_LDS16(ga + (size_t)64 * K, &As[0][sr + 64][sc]);
    GLOAD_LDS16(gb, &Bs[0][sr][sc]);
    GLOAD_LDS16(gb + (size_t)64 * K, &Bs[0][sr + 64][sc]);
    __syncthreads();

    int cur = 0;
    for (int k0 = 0; k0 < K; k0 += 32) {
        if (k0 + 32 < K) {
            const bf16_t* ga2 = ga + k0 + 32;
            const bf16_t* gb2 = gb + k0 + 32;
            GLOAD_LDS16(ga2, &As[cur ^ 1][sr][sc]);
            GLOAD_LDS16(ga2 + (size_t)64 * K, &As[cur ^ 1][sr + 64][sc]);
            GLOAD_LDS16(gb2, &Bs[cur ^ 1][sr][sc]);
            GLOAD_LDS16(gb2 + (size_t)64 * K, &Bs[cur ^ 1][sr + 64][sc]);
        }
        bf16x8 af[4], bfr[4];
#pragma unroll
        for (int r = 0; r < 4; r++) af[r] = *(const bf16x8*)&As[cur][mrow + r * 16 + lm][q4 * 8];
#pragma unroll
        for (int c = 0; c < 4; c++) bfr[c] = *(const bf16x8*)&Bs[cur][ncol + c * 16 + lm][q4 * 8];
#pragma unroll
        for (int r = 0; r < 4; r++)
#pragma unroll
            for (int c = 0; c < 4; c++) acc[r][c] = mfma16(af[r], bfr[c], acc[r][c]);
        __syncthreads();
        cur ^= 1;
    }

#pragma unroll
    for (int r = 0; r < 4; r++)
#pragma unroll
        for (int c = 0; c < 4; c++)
#pragma unroll
            for (int i = 0; i < 4; i++) {
                int m = mblk + mrow + r * 16 + q4 * 4 + i;
                int n = nblk + ncol + c * 16 + lm;
                float v = acc[r][c][i] + bias[n];
                outp[(size_t)m * N + n] = v + resid[(size_t)m * N + n];
            }
}

// ---------- FUSED attn: QK^T/8 -> S(LDS) -> blend+softmax (coalesced, prefetched)
//            -> P in-place in S -> PV MFMA -> xo
// grid: (S/16=32, B*H=128); block 256 = 4 waves. LDS = 33 KB -> 4 blocks/CU.
// Stride 516 f32: bank start = 4*(lm+q4) mod 32 -> all phases hit 8 balanced windows.
__global__ __launch_bounds__(256, 4) void attn_fused_kernel(const bf16_t* __restrict__ Qb,
                                                            const bf16_t* __restrict__ Kb,
                                                            const bf16_t* __restrict__ Vt,
                                                            const float* __restrict__ help_vals,
                                                            const int* __restrict__ help_mask,
                                                            const int* __restrict__ attn_mask,
                                                            float* __restrict__ attn_out,
                                                            bf16_t* __restrict__ xo) {
    constexpr int SS = 516;
    const int t = threadIdx.x;
    const int lane = t & 63, wv = t >> 6;
    const int lm = lane & 15, q4 = lane >> 4;
    const int bh = blockIdx.y;
    const int b = bh >> 4, h = bh & 15;
    const int q0 = blockIdx.x * 16;
    const bf16_t* Qp = Qb + (size_t)bh * 512 * 64;
    const bf16_t* Kp = Kb + (size_t)bh * 512 * 64;
    const bf16_t* Vp = Vt + (size_t)bh * 64 * 512;  // [dk][s]

    __shared__ float S[16][SS];  // 33 KB; P written in place; red overlays after barrier

    const int c0 = lane * 4, c1 = 256 + lane * 4;
    const int rbase = wv * 4;
    const size_t qrow0 = ((size_t)bh * 512 + q0 + rbase) * 512;
    const size_t arow0 = ((size_t)b * 512 + q0 + rbase) * 512;

    // T14: issue row-0 streaming loads before phase 1 (NT: single-use streams)
    f32x4 hv[2][2];
    i32x4 hm[2][2], am[2][2];
    hv[0][0] = __builtin_nontemporal_load((const f32x4*)&help_vals[qrow0 + c0]);
    hv[0][1] = __builtin_nontemporal_load((const f32x4*)&help_vals[qrow0 + c1]);
    hm[0][0] = __builtin_nontemporal_load((const i32x4*)&help_mask[qrow0 + c0]);
    hm[0][1] = __builtin_nontemporal_load((const i32x4*)&help_mask[qrow0 + c1]);
    am[0][0] = *(const i32x4*)&attn_mask[arow0 + c0];
    am[0][1] = *(const i32x4*)&attn_mask[arow0 + c1];

    // ---- phase 1: QK^T (A = K rows -> D row=key, B = Q rows -> D col=q) ----
    const bf16x8 bq0 = *(const bf16x8*)&Qp[(size_t)(q0 + lm) * 64 + q4 * 8];
    const bf16x8 bq1 = *(const bf16x8*)&Qp[(size_t)(q0 + lm) * 64 + 32 + q4 * 8];
    f32x4 acc[8];
#pragma unroll
    for (int kt = 0; kt < 8; kt++) acc[kt] = (f32x4){0.f, 0.f, 0.f, 0.f};
    __builtin_amdgcn_s_setprio(1);
#pragma unroll
    for (int kt = 0; kt < 8; kt++) {
        const int krow = wv * 128 + kt * 16 + lm;
        bf16x8 ak0 = *(const bf16x8*)&Kp[(size_t)krow * 64 + q4 * 8];
        bf16x8 ak1 = *(const bf16x8*)&Kp[(size_t)krow * 64 + 32 + q4 * 8];
        acc[kt] = mfma16(ak0, bq0, acc[kt]);
        acc[kt] = mfma16(ak1, bq1, acc[kt]);
    }
    __builtin_amdgcn_s_setprio(0);
#pragma unroll
    for (int kt = 0; kt < 8; kt++)
        *(f32x4*)&S[lm][wv * 128 + kt * 16 + q4 * 4] = acc[kt] * 0.125f;
    __syncthreads();

    // ---- phase 2: blend + softmax, 4 q rows per wave, prefetch-pipelined ----
#pragma unroll
    for (int rr = 0; rr < 4; rr++) {
        const int sl = rr & 1, sn = sl ^ 1;
        if (rr < 3) {  // prefetch next row's streams
            const size_t qr = qrow0 + (size_t)(rr + 1) * 512;
            const size_t ar = arow0 + (size_t)(rr + 1) * 512;
            hv[sn][0] = __builtin_nontemporal_load((const f32x4*)&help_vals[qr + c0]);
            hv[sn][1] = __builtin_nontemporal_load((const f32x4*)&help_vals[qr + c1]);
            hm[sn][0] = __builtin_nontemporal_load((const i32x4*)&help_mask[qr + c0]);
            hm[sn][1] = __builtin_nontemporal_load((const i32x4*)&help_mask[qr + c1]);
            am[sn][0] = *(const i32x4*)&attn_mask[ar + c0];
            am[sn][1] = *(const i32x4*)&attn_mask[ar + c1];
        }
        const int r = rbase + rr;
        const size_t qrow = qrow0 + (size_t)rr * 512;
        f32x4 s0 = *(const f32x4*)&S[r][c0];
        f32x4 s1 = *(const f32x4*)&S[r][c1];
        float sv[8];
#pragma unroll
        for (int i = 0; i < 4; i++) sv[i] = blendf(s0[i], am[sl][0][i], hm[sl][0][i], hv[sl][0][i]);
#pragma unroll
        for (int i = 0; i < 4; i++)
            sv[4 + i] = blendf(s1[i], am[sl][1][i], hm[sl][1][i], hv[sl][1][i]);
        float mloc = fmaxf(fmaxf(fmaxf(sv[0], sv[1]), fmaxf(sv[2], sv[3])),
                           fmaxf(fmaxf(sv[4], sv[5]), fmaxf(sv[6], sv[7])));
#pragma unroll
        for (int off = 1; off < 64; off <<= 1) mloc = fmaxf(mloc, __shfl_xor(mloc, off));
        float lsum = 0.f;
#pragma unroll
        for (int i = 0; i < 8; i++) {
            sv[i] = __expf(sv[i] - mloc);
            lsum += sv[i];
        }
#pragma unroll
        for (int off = 1; off < 64; off <<= 1) lsum += __shfl_xor(lsum, off);
        const float rinv = 1.0f / lsum;
        f32x4 o0, o1;
        o0[0] = sv[0] * rinv; o0[1] = sv[1] * rinv; o0[2] = sv[2] * rinv; o0[3] = sv[3] * rinv;
        o1[0] = sv[4] * rinv; o1[1] = sv[5] * rinv; o1[2] = sv[6] * rinv; o1[3] = sv[7] * rinv;
        *(f32x4*)&S[r][c0] = o0;  // normalized P in place (same wave, same row)
        *(f32x4*)&S[r][c1] = o1;
        __builtin_nontemporal_store(o0, (f32x4*)&attn_out[qrow + c0]);
        __builtin_nontemporal_store(o1, (f32x4*)&attn_out[qrow + c1]);
    }
    __syncthreads();

    // ---- phase 3: PV. A = V^T rows (d), B = P^T (f32->bf16 on the fly) ----
    f32x4 acc2[4];
#pragma unroll
    for (int mt = 0; mt < 4; mt++) acc2[mt] = (f32x4){0.f, 0.f, 0.f, 0.f};
    const int kb0 = wv * 128;
    __builtin_amdgcn_s_setprio(1);
#pragma unroll
    for (int C = 0; C < 4; C++) {
        f32x4 pa = *(const f32x4*)&S[lm][kb0 + C * 32 + q4 * 8];
        f32x4 pb = *(const f32x4*)&S[lm][kb0 + C * 32 + q4 * 8 + 4];
        bf16x8 pf;
        pf[0] = (bf16_t)pa[0]; pf[1] = (bf16_t)pa[1]; pf[2] = (bf16_t)pa[2]; pf[3] = (bf16_t)pa[3];
        pf[4] = (bf16_t)pb[0]; pf[5] = (bf16_t)pb[1]; pf[6] = (bf16_t)pb[2]; pf[7] = (bf16_t)pb[3];
#pragma unroll
        for (int mt = 0; mt < 4; mt++) {
            const bf16x8 vf =
                *(const bf16x8*)&Vp[(size_t)(mt * 16 + lm) * 512 + kb0 + C * 32 + q4 * 8];
            acc2[mt] = mfma16(vf, pf, acc2[mt]);
        }
    }
    __builtin_amdgcn_s_setprio(0);
    __syncthreads();  // all P reads done before red overlays S

    // ---- phase 4: cross-wave reduce through LDS (red[4][16][68] overlays S) ----
    float* redp = &S[0][0];
#pragma unroll
    for (int mt = 0; mt < 4; mt++)
        *(f32x4*)(redp + ((wv * 16 + lm) * 68 + mt * 16 + q4 * 4)) = acc2[mt];
    __syncthreads();
    {
        const int qq = t >> 4;
        const int d4 = (t & 15) * 4;
        f32x4 r0 = *(const f32x4*)(redp + ((0 * 16 + qq) * 68 + d4));
        f32x4 r1 = *(const f32x4*)(redp + ((1 * 16 + qq) * 68 + d4));
        f32x4 r2 = *(const f32x4*)(redp + ((2 * 16 + qq) * 68 + d4));
        f32x4 r3 = *(const f32x4*)(redp + ((3 * 16 + qq) * 68 + d4));
        f32x4 sum = r0 + r1 + r2 + r3;
        bf16x4 o;
        o[0] = (bf16_t)sum[0]; o[1] = (bf16_t)sum[1];
        o[2] = (bf16_t)sum[2]; o[3] = (bf16_t)sum[3];
        *(bf16x4*)&xo[((size_t)(b * 512 + q0 + qq)) * 1024 + h * 64 + d4] = o;
    }
}

// ---------- LayerNorm over last dim (1024) ----------
__global__ __launch_bounds__(256) void layernorm_kernel(const float* __restrict__ ypre,
                                                        const float* __restrict__ g,
                                                        const float* __restrict__ bvec,
                                                        float* __restrict__ out) {
    int row = blockIdx.x;
    int t = threadIdx.x;
    float4 v = ((const float4*)(ypre + (size_t)row * 1024))[t];
    float s = v.x + v.y + v.z + v.w;
    float sq = v.x * v.x + v.y * v.y + v.z * v.z + v.w * v.w;
#pragma unroll
    for (int off = 32; off; off >>= 1) {
        s += __shfl_down(s, off);
        sq += __shfl_down(sq, off);
    }
    __shared__ float ss[4], ssq[4];
    if ((t & 63) == 0) { ss[t >> 6] = s; ssq[t >> 6] = sq; }
    __syncthreads();
    float tot = ss[0] + ss[1] + ss[2] + ss[3];
    float totq = ssq[0] + ssq[1] + ssq[2] + ssq[3];
    float mu = tot * (1.0f / 1024.0f);
    float var = totq * (1.0f / 1024.0f) - mu * mu;
    float rstd = rsqrtf(var + 1e-5f);
    float4 gg = ((const float4*)g)[t];
    float4 bb = ((const float4*)bvec)[t];
    float4 o;
    o.x = (v.x - mu) * rstd * gg.x + bb.x;
    o.y = (v.y - mu) * rstd * gg.y + bb.y;
    o.z = (v.z - mu) * rstd * gg.z + bb.z;
    o.w = (v.w - mu) * rstd * gg.w + bb.w;
    ((float4*)(out + (size_t)row * 1024))[t] = o;
}

extern "C" void kernel_launch(void* const* d_in, const int* in_sizes, int n_in,
                              void* d_out, int out_size, void* d_ws, size_t ws_size,
                              hipStream_t stream) {
    const float* x         = (const float*)d_in[0];
    const float* Wq        = (const float*)d_in[1];
    const float* bq        = (const float*)d_in[2];
    const float* Wk        = (const float*)d_in[3];
    const float* bk        = (const float*)d_in[4];
    const float* Wv        = (const float*)d_in[5];
    const float* bv        = (const float*)d_in[6];
    const float* Wo        = (const float*)d_in[7];
    const float* bo        = (const float*)d_in[8];
    const float* ln_g      = (const float*)d_in[9];
    const float* ln_b      = (const float*)d_in[10];
    const float* help_vals = (const float*)d_in[11];
    const int*   help_mask = (const int*)d_in[12];
    const int*   attn_mask = (const int*)d_in[13];

    char* ws = (char*)d_ws;
    bf16_t* xb   = (bf16_t*)(ws);                       // 8 MB  [4096,1024]
    bf16_t* wqt  = (bf16_t*)(ws + ((size_t)8 << 20));   // 4x2MB [1024,1024] N-major, contiguous
    bf16_t* wot  = (bf16_t*)(ws + ((size_t)14 << 20));
    bf16_t* qb   = (bf16_t*)(ws + ((size_t)16 << 20));  // 8 MB  [B,H,S,DK]
    bf16_t* kb   = (bf16_t*)(ws + ((size_t)24 << 20));  // 8 MB  [B,H,S,DK]
    bf16_t* vt   = (bf16_t*)(ws + ((size_t)32 << 20));  // 8 MB  [B,H,DK,S]
    bf16_t* xo   = (bf16_t*)(ws + ((size_t)40 << 20));  // 8 MB  [B,S,H*DK]
    float*  ypre = (float*)(ws + ((size_t)48 << 20));   // 16 MB [4096,1024]

    float* y_out = (float*)d_out;                      // [B,S,D] f32
    float* attn_out = y_out + (size_t)4096 * 1024;     // [B,H,S,S] f32

    cast_kernel<<<4096, 256, 0, stream>>>(x, xb);
    transpose_kernel<<<dim3(32, 32, 4), 256, 0, stream>>>(Wq, Wk, Wv, Wo, wqt);

    gemm_qkv<<<dim3(8, 32, 3), 256, 0, stream>>>(xb, wqt, bq, bk, bv, qb, kb, vt);

    attn_fused_kernel<<<dim3(32, 128), 256, 0, stream>>>(qb, kb, vt, help_vals, help_mask,
                                                         attn_mask, attn_out, xo);

    gemm_out<<<dim3(8, 32), 256, 0, stream>>>(xo, wot, bo, x, ypre);
    layernorm_kernel<<<4096, 256, 0, stream>>>(ypre, ln_g, ln_b, y_out);
}